// Round 14
// baseline (75.662 us; speedup 1.0000x reference)
//
#include <hip/hip_runtime.h>

#define TT 28
#define II 28
#define HH 64
#define OO 10

typedef __attribute__((ext_vector_type(8))) __bf16 bf16x8;
typedef __attribute__((ext_vector_type(2))) __bf16 bf16x2;
typedef __attribute__((ext_vector_type(4))) float f32x4;
typedef __attribute__((ext_vector_type(4))) unsigned int u32x4;

#define MFMA(A, B, C) __builtin_amdgcn_mfma_f32_16x16x32_bf16((A), (B), (C), 0, 0, 0)

__device__ __forceinline__ unsigned cvtpk(float lo, float hi) {
    bf16x2 p; p.x = (__bf16)lo; p.y = (__bf16)hi;   // v_cvt_pk_bf16_f32 (RTNE)
    return __builtin_bit_cast(unsigned, p);
}

struct PK3 { unsigned p0, p1, p2; };
// 3-limb bf16 pair split: residuals exact, total representation error O(2^-27).
__device__ __forceinline__ PK3 split3pk(float a, float b) {
    PK3 r;
    r.p0 = cvtpk(a, b);
    float a0 = __builtin_bit_cast(float, r.p0 << 16);
    float b0 = __builtin_bit_cast(float, r.p0 & 0xFFFF0000u);
    float ra = a - a0, rb = b - b0;
    r.p1 = cvtpk(ra, rb);
    float a1 = __builtin_bit_cast(float, r.p1 << 16);
    float b1 = __builtin_bit_cast(float, r.p1 & 0xFFFF0000u);
    r.p2 = cvtpk(ra - a1, rb - b1);
    return r;
}
__device__ __forceinline__ bf16x8 asbf(u32x4 u) {
    return __builtin_bit_cast(bf16x8, u);
}

__device__ __forceinline__ void mk3(const float4& A, const float4& B,
                                    bf16x8& l0, bf16x8& l1, bf16x8& l2) {
    u32x4 u0, u1, u2;
    PK3 s;
    s = split3pk(A.x, A.y); u0.x = s.p0; u1.x = s.p1; u2.x = s.p2;
    s = split3pk(A.z, A.w); u0.y = s.p0; u1.y = s.p1; u2.y = s.p2;
    s = split3pk(B.x, B.y); u0.z = s.p0; u1.z = s.p1; u2.z = s.p2;
    s = split3pk(B.z, B.w); u0.w = s.p0; u1.w = s.p1; u2.w = s.p2;
    l0 = asbf(u0); l1 = asbf(u1); l2 = asbf(u2);
}

// Transposed-recurrence MFMA RNN, permuted rows, 3-limb numerics (r11/r13 class).
// Round 14: dual aH accumulators (8 independent depth-6 MFMA chains, jt-round-robin
// issue) + software-pipelined x-projection (aX(t+1) computed during step t) +
// x prefetch distance 2. SINGLE-WAVE ONLY. No LDS, no barriers.
__global__ __launch_bounds__(256, 2) void rnn_mfma11(
    const float* __restrict__ X, const float* __restrict__ W_ih,
    const float* __restrict__ W_hh, const float* __restrict__ b_ih,
    const float* __restrict__ b_hh, const float* __restrict__ W_out,
    const float* __restrict__ b_out, float* __restrict__ out)
{
    const int lane = threadIdx.x & 63;
    const int wave = threadIdx.x >> 6;
    const int m15  = lane & 15;
    const int g    = lane >> 4;
    const int bglob = blockIdx.x * 64 + wave * 16 + m15;
    const int rowhi = 8 * (m15 >> 2) + (m15 & 3);

    // ---- W_hh A-fragments, 3-limb, permuted rows ----
    bf16x8 whh0[4][2], whh1[4][2], whh2[4][2];
    #pragma unroll
    for (int jt = 0; jt < 4; ++jt) {
        const int jA = 32 * (jt >> 1) + 4 * (jt & 1) + rowhi;
        #pragma unroll
        for (int kb = 0; kb < 2; ++kb) {
            const float* p = W_hh + jA * HH + 32 * kb + 8 * g;
            float4 a = *(const float4*)p;
            float4 c = *(const float4*)(p + 4);
            mk3(a, c, whh0[jt][kb], whh1[jt][kb], whh2[jt][kb]);
        }
    }

    // ---- W_ih A-fragments, K padded to 32 (k=28 carries bias), 3-limb ----
    bf16x8 wih0[4], wih1[4], wih2[4];
    #pragma unroll
    for (int jt = 0; jt < 4; ++jt) {
        const int jA = 32 * (jt >> 1) + 4 * (jt & 1) + rowhi;
        float wv[8];
        #pragma unroll
        for (int e = 0; e < 8; ++e) {
            int k = 8 * g + e;
            float v = 0.f;
            if (k < II)       v = W_ih[jA * II + k];
            else if (k == II) v = b_ih[jA] + b_hh[jA];
            wv[e] = v;
        }
        float4 a = {wv[0], wv[1], wv[2], wv[3]};
        float4 c = {wv[4], wv[5], wv[6], wv[7]};
        mk3(a, c, wih0[jt], wih1[jt], wih2[jt]);
    }

    const float* xbase = X + (size_t)bglob * (TT * II);

    f32x4 axc[4];
    float4 xA, xB, nA, nB;

    // ---- preamble: xs(0) -> axc = aX(0); load x(1) ----
    {
        const float* p = xbase + 8 * g;
        float4 r0 = *(const float4*)p;
        float4 r1 = (g < 3) ? *(const float4*)(p + 4) : make_float4(1.f, 0.f, 0.f, 0.f);
        bf16x8 xs0, xs1, xs2;
        mk3(r0, r1, xs0, xs1, xs2);
        f32x4 z = {0.f, 0.f, 0.f, 0.f};
        axc[0] = z; axc[1] = z; axc[2] = z; axc[3] = z;
        #pragma unroll
        for (int jt = 0; jt < 4; ++jt) axc[jt] = MFMA(wih0[jt], xs0, axc[jt]);
        #pragma unroll
        for (int jt = 0; jt < 4; ++jt) axc[jt] = MFMA(wih0[jt], xs1, axc[jt]);
        #pragma unroll
        for (int jt = 0; jt < 4; ++jt) axc[jt] = MFMA(wih1[jt], xs0, axc[jt]);
        #pragma unroll
        for (int jt = 0; jt < 4; ++jt) axc[jt] = MFMA(wih0[jt], xs2, axc[jt]);
        #pragma unroll
        for (int jt = 0; jt < 4; ++jt) axc[jt] = MFMA(wih1[jt], xs1, axc[jt]);
        #pragma unroll
        for (int jt = 0; jt < 4; ++jt) axc[jt] = MFMA(wih2[jt], xs0, axc[jt]);

        const float* q = xbase + II + 8 * g;
        xA = *(const float4*)q;
        xB = (g < 3) ? *(const float4*)(q + 4) : make_float4(1.f, 0.f, 0.f, 0.f);
    }

    bf16x8 h0[2], h1[2], h2[2];
    float th[4][4];

    for (int t = 0; t < TT; ++t) {
        // 1. issue load x(t+2) (clamped; redundant on last iterations)
        {
            const int tl = (t + 2 < TT) ? (t + 2) : (TT - 1);
            const float* p = xbase + tl * II + 8 * g;
            nA = *(const float4*)p;
            nB = (g < 3) ? *(const float4*)(p + 4) : make_float4(1.f, 0.f, 0.f, 0.f);
        }

        // 2. aH: 8 independent depth-6 chains, jt-round-robin issue
        f32x4 z = {0.f, 0.f, 0.f, 0.f};
        f32x4 aHa[4] = {z, z, z, z}, aHb[4] = {z, z, z, z};
        if (t > 0) {
            #pragma unroll
            for (int jt = 0; jt < 4; ++jt) { aHa[jt] = MFMA(whh0[jt][0], h0[0], aHa[jt]);
                                             aHb[jt] = MFMA(whh0[jt][1], h0[1], aHb[jt]); }
            #pragma unroll
            for (int jt = 0; jt < 4; ++jt) { aHa[jt] = MFMA(whh0[jt][0], h1[0], aHa[jt]);
                                             aHb[jt] = MFMA(whh0[jt][1], h1[1], aHb[jt]); }
            #pragma unroll
            for (int jt = 0; jt < 4; ++jt) { aHa[jt] = MFMA(whh1[jt][0], h0[0], aHa[jt]);
                                             aHb[jt] = MFMA(whh1[jt][1], h0[1], aHb[jt]); }
            #pragma unroll
            for (int jt = 0; jt < 4; ++jt) { aHa[jt] = MFMA(whh0[jt][0], h2[0], aHa[jt]);
                                             aHb[jt] = MFMA(whh0[jt][1], h2[1], aHb[jt]); }
            #pragma unroll
            for (int jt = 0; jt < 4; ++jt) { aHa[jt] = MFMA(whh1[jt][0], h1[0], aHa[jt]);
                                             aHb[jt] = MFMA(whh1[jt][1], h1[1], aHb[jt]); }
            #pragma unroll
            for (int jt = 0; jt < 4; ++jt) { aHa[jt] = MFMA(whh2[jt][0], h0[0], aHa[jt]);
                                             aHb[jt] = MFMA(whh2[jt][1], h0[1], aHb[jt]); }
        }

        // 3+4. pipelined x-projection for t+1 (independent of h)
        f32x4 axn[4] = {z, z, z, z};
        if (t < TT - 1) {
            bf16x8 nx0, nx1, nx2;
            mk3(xA, xB, nx0, nx1, nx2);
            #pragma unroll
            for (int jt = 0; jt < 4; ++jt) axn[jt] = MFMA(wih0[jt], nx0, axn[jt]);
            #pragma unroll
            for (int jt = 0; jt < 4; ++jt) axn[jt] = MFMA(wih0[jt], nx1, axn[jt]);
            #pragma unroll
            for (int jt = 0; jt < 4; ++jt) axn[jt] = MFMA(wih1[jt], nx0, axn[jt]);
            #pragma unroll
            for (int jt = 0; jt < 4; ++jt) axn[jt] = MFMA(wih0[jt], nx2, axn[jt]);
            #pragma unroll
            for (int jt = 0; jt < 4; ++jt) axn[jt] = MFMA(wih1[jt], nx1, axn[jt]);
            #pragma unroll
            for (int jt = 0; jt < 4; ++jt) axn[jt] = MFMA(wih2[jt], nx0, axn[jt]);
        }

        // 5. tanh((axc + aHa) + aHb): PROVEN ocml path
        #pragma unroll
        for (int jt = 0; jt < 4; ++jt) {
            f32x4 s = (axc[jt] + aHa[jt]) + aHb[jt];
            #pragma unroll
            for (int r = 0; r < 4; ++r) {
                float e = __expf(2.f * s[r]);
                th[jt][r] = 1.f - 2.f * __builtin_amdgcn_rcpf(e + 1.f);
            }
        }

        // 6. next-step h B-fragments (lane-local, 3-limb)
        if (t < TT - 1) {
            #pragma unroll
            for (int kb = 0; kb < 2; ++kb) {
                float4 a = {th[2 * kb][0], th[2 * kb][1], th[2 * kb][2], th[2 * kb][3]};
                float4 c = {th[2 * kb + 1][0], th[2 * kb + 1][1],
                            th[2 * kb + 1][2], th[2 * kb + 1][3]};
                mk3(a, c, h0[kb], h1[kb], h2[kb]);
            }
        }

        // 7. rotate pipelines
        axc[0] = axn[0]; axc[1] = axn[1]; axc[2] = axn[2]; axc[3] = axn[3];
        xA = nA; xB = nB;
    }

    // ---- output head ----
    float po[OO];
    #pragma unroll
    for (int o = 0; o < OO; ++o) {
        float s = 0.f;
        #pragma unroll
        for (int jt = 0; jt < 4; ++jt) {
            const float* wp = W_out + o * HH + 32 * (jt >> 1) + 8 * g + 4 * (jt & 1);
            float4 wv = *(const float4*)wp;
            s += th[jt][0] * wv.x + th[jt][1] * wv.y +
                 th[jt][2] * wv.z + th[jt][3] * wv.w;
        }
        s += __shfl_xor(s, 16);
        s += __shfl_xor(s, 32);
        po[o] = s;
    }
    if (g == 0) {
        #pragma unroll
        for (int o = 0; o < OO; ++o)
            out[(size_t)bglob * OO + o] = po[o] + b_out[o];
    }
}

extern "C" void kernel_launch(void* const* d_in, const int* in_sizes, int n_in,
                              void* d_out, int out_size, void* d_ws, size_t ws_size,
                              hipStream_t stream) {
    const float* X     = (const float*)d_in[0];
    const float* W_ih  = (const float*)d_in[1];
    const float* W_hh  = (const float*)d_in[2];
    const float* b_ih  = (const float*)d_in[3];
    const float* b_hh  = (const float*)d_in[4];
    const float* W_out = (const float*)d_in[5];
    const float* b_out = (const float*)d_in[6];
    float* out = (float*)d_out;

    const int B = in_sizes[0] / (TT * II);   // 32768
    dim3 grid(B / 64), block(256);           // 4 waves x 16 batch elems per block
    hipLaunchKernelGGL(rnn_mfma11, grid, block, 0, stream,
                       X, W_ih, W_hh, b_ih, b_hh, W_out, b_out, out);
}

// Round 15
// 68.200 us; speedup vs baseline: 1.1094x; 1.1094x over previous
//
#include <hip/hip_runtime.h>

#define TT 28
#define II 28
#define HH 64
#define OO 10

typedef __attribute__((ext_vector_type(8))) __bf16 bf16x8;
typedef __attribute__((ext_vector_type(2))) __bf16 bf16x2;
typedef __attribute__((ext_vector_type(4))) float f32x4;
typedef __attribute__((ext_vector_type(4))) unsigned int u32x4;

#define MFMA(A, B, C) __builtin_amdgcn_mfma_f32_16x16x32_bf16((A), (B), (C), 0, 0, 0)

__device__ __forceinline__ unsigned cvtpk(float lo, float hi) {
    bf16x2 p; p.x = (__bf16)lo; p.y = (__bf16)hi;   // v_cvt_pk_bf16_f32 (RTNE)
    return __builtin_bit_cast(unsigned, p);
}

struct PK3 { unsigned p0, p1, p2; };
// 3-limb bf16 pair split: residuals exact, total representation error O(2^-27).
__device__ __forceinline__ PK3 split3pk(float a, float b) {
    PK3 r;
    r.p0 = cvtpk(a, b);
    float a0 = __builtin_bit_cast(float, r.p0 << 16);
    float b0 = __builtin_bit_cast(float, r.p0 & 0xFFFF0000u);
    float ra = a - a0, rb = b - b0;
    r.p1 = cvtpk(ra, rb);
    float a1 = __builtin_bit_cast(float, r.p1 << 16);
    float b1 = __builtin_bit_cast(float, r.p1 & 0xFFFF0000u);
    r.p2 = cvtpk(ra - a1, rb - b1);
    return r;
}
__device__ __forceinline__ bf16x8 asbf(u32x4 u) {
    return __builtin_bit_cast(bf16x8, u);
}

// Transposed-recurrence MFMA RNN, permuted rows, 3-limb numerics — the r13
// kernel (passed, absmax 0.00195 = fp32 floor, 69 us) with ONE change:
// amdgpu_waves_per_eu(2,2) pins occupancy to the grid-supplied 2 waves/SIMD,
// raising the VGPR cap to 256 so the 144-reg W fragment set stays RESIDENT
// (r13's VGPR=112 proves the allocator was rematerializing W inside the
// t-loop — the hidden per-step cost that made r13's split-opt a null).
// SINGLE-WAVE ONLY (j/k-split exchange: 0 for 5). No LDS, no barriers.
// tanh: proven ocml __expf path (raw v_exp_f32 insufficient — r10).
__global__ __attribute__((amdgpu_waves_per_eu(2, 2))) __launch_bounds__(256)
void rnn_mfma12(
    const float* __restrict__ X, const float* __restrict__ W_ih,
    const float* __restrict__ W_hh, const float* __restrict__ b_ih,
    const float* __restrict__ b_hh, const float* __restrict__ W_out,
    const float* __restrict__ b_out, float* __restrict__ out)
{
    const int lane = threadIdx.x & 63;
    const int wave = threadIdx.x >> 6;
    const int m15  = lane & 15;        // batch col for B/C, row-within-tile for A
    const int g    = lane >> 4;        // k-group / C row-group
    const int bglob = blockIdx.x * 64 + wave * 16 + m15;
    const int rowhi = 8 * (m15 >> 2) + (m15 & 3);   // permuted-row component

    // ---- W_hh A-fragments, 3-limb, permuted rows ----
    bf16x8 whh0[4][2], whh1[4][2], whh2[4][2];
    #pragma unroll
    for (int jt = 0; jt < 4; ++jt) {
        const int jA = 32 * (jt >> 1) + 4 * (jt & 1) + rowhi;
        #pragma unroll
        for (int kb = 0; kb < 2; ++kb) {
            const float* p = W_hh + jA * HH + 32 * kb + 8 * g;
            float4 a = *(const float4*)p;
            float4 c = *(const float4*)(p + 4);
            u32x4 u0, u1, u2;
            PK3 s;
            s = split3pk(a.x, a.y); u0.x = s.p0; u1.x = s.p1; u2.x = s.p2;
            s = split3pk(a.z, a.w); u0.y = s.p0; u1.y = s.p1; u2.y = s.p2;
            s = split3pk(c.x, c.y); u0.z = s.p0; u1.z = s.p1; u2.z = s.p2;
            s = split3pk(c.z, c.w); u0.w = s.p0; u1.w = s.p1; u2.w = s.p2;
            whh0[jt][kb] = asbf(u0); whh1[jt][kb] = asbf(u1); whh2[jt][kb] = asbf(u2);
        }
    }

    // ---- W_ih A-fragments, K padded to 32 (k=28 carries bias), 3-limb ----
    bf16x8 wih0[4], wih1[4], wih2[4];
    #pragma unroll
    for (int jt = 0; jt < 4; ++jt) {
        const int jA = 32 * (jt >> 1) + 4 * (jt & 1) + rowhi;
        float wv[8];
        #pragma unroll
        for (int e = 0; e < 8; ++e) {
            int k = 8 * g + e;
            float v = 0.f;
            if (k < II)       v = W_ih[jA * II + k];
            else if (k == II) v = b_ih[jA] + b_hh[jA];
            wv[e] = v;
        }
        u32x4 u0, u1, u2;
        PK3 s;
        s = split3pk(wv[0], wv[1]); u0.x = s.p0; u1.x = s.p1; u2.x = s.p2;
        s = split3pk(wv[2], wv[3]); u0.y = s.p0; u1.y = s.p1; u2.y = s.p2;
        s = split3pk(wv[4], wv[5]); u0.z = s.p0; u1.z = s.p1; u2.z = s.p2;
        s = split3pk(wv[6], wv[7]); u0.w = s.p0; u1.w = s.p1; u2.w = s.p2;
        wih0[jt] = asbf(u0); wih1[jt] = asbf(u1); wih2[jt] = asbf(u2);
    }

    const float* xbase = X + (size_t)bglob * (TT * II);

    // prefetch x for t=0 (k=28 is the bias column: x28 = 1)
    float4 xr0, xr1;
    {
        const float* p = xbase + 8 * g;
        xr0 = *(const float4*)p;
        xr1 = (g < 3) ? *(const float4*)(p + 4) : make_float4(1.f, 0.f, 0.f, 0.f);
    }

    bf16x8 h0[2], h1[2], h2[2];   // h B-fragments (3-limb), valid for t>=1
    float th[4][4];

    for (int t = 0; t < TT; ++t) {
        // ---- x B-fragments (3-limb, pair-packed) ----
        bf16x8 xs0, xs1, xs2;
        {
            u32x4 u0, u1, u2;
            PK3 s;
            s = split3pk(xr0.x, xr0.y); u0.x = s.p0; u1.x = s.p1; u2.x = s.p2;
            s = split3pk(xr0.z, xr0.w); u0.y = s.p0; u1.y = s.p1; u2.y = s.p2;
            s = split3pk(xr1.x, xr1.y); u0.z = s.p0; u1.z = s.p1; u2.z = s.p2;
            s = split3pk(xr1.z, xr1.w); u0.w = s.p0; u1.w = s.p1; u2.w = s.p2;
            xs0 = asbf(u0); xs1 = asbf(u1); xs2 = asbf(u2);
        }

        // prefetch next t
        if (t < TT - 1) {
            const float* p = xbase + (t + 1) * II + 8 * g;
            xr0 = *(const float4*)p;
            xr1 = (g < 3) ? *(const float4*)(p + 4) : make_float4(1.f, 0.f, 0.f, 0.f);
        }

        // ---- per tile: x-proj chain (6 products) + recurrent chain (2x6) ----
        #pragma unroll
        for (int jt = 0; jt < 4; ++jt) {
            f32x4 aX = {0.f, 0.f, 0.f, 0.f};
            aX = MFMA(wih0[jt], xs0, aX);
            aX = MFMA(wih0[jt], xs1, aX);
            aX = MFMA(wih1[jt], xs0, aX);
            aX = MFMA(wih0[jt], xs2, aX);
            aX = MFMA(wih1[jt], xs1, aX);
            aX = MFMA(wih2[jt], xs0, aX);
            if (t > 0) {
                f32x4 aH = {0.f, 0.f, 0.f, 0.f};
                #pragma unroll
                for (int kb = 0; kb < 2; ++kb) {
                    aH = MFMA(whh0[jt][kb], h0[kb], aH);
                    aH = MFMA(whh0[jt][kb], h1[kb], aH);
                    aH = MFMA(whh1[jt][kb], h0[kb], aH);
                    aH = MFMA(whh0[jt][kb], h2[kb], aH);
                    aH = MFMA(whh1[jt][kb], h1[kb], aH);
                    aH = MFMA(whh2[jt][kb], h0[kb], aH);
                }
                aX = aX + aH;
            }
            // ---- tanh: PROVEN ocml path ----
            #pragma unroll
            for (int r = 0; r < 4; ++r) {
                float aa = aX[r];
                float e = __expf(2.f * aa);
                th[jt][r] = 1.f - 2.f * __builtin_amdgcn_rcpf(e + 1.f);
            }
        }

        // ---- next-step h B-fragments: lane-local, 3-limb, pair-packed ----
        if (t < TT - 1) {
            #pragma unroll
            for (int kb = 0; kb < 2; ++kb) {
                u32x4 u0, u1, u2;
                PK3 s;
                s = split3pk(th[2 * kb][0], th[2 * kb][1]);
                u0.x = s.p0; u1.x = s.p1; u2.x = s.p2;
                s = split3pk(th[2 * kb][2], th[2 * kb][3]);
                u0.y = s.p0; u1.y = s.p1; u2.y = s.p2;
                s = split3pk(th[2 * kb + 1][0], th[2 * kb + 1][1]);
                u0.z = s.p0; u1.z = s.p1; u2.z = s.p2;
                s = split3pk(th[2 * kb + 1][2], th[2 * kb + 1][3]);
                u0.w = s.p0; u1.w = s.p1; u2.w = s.p2;
                h0[kb] = asbf(u0); h1[kb] = asbf(u1); h2[kb] = asbf(u2);
            }
        }
    }

    // ---- output head: out[b,o] = h . W_out[o,:] + b_out[o] (permuted j) ----
    float po[OO];
    #pragma unroll
    for (int o = 0; o < OO; ++o) {
        float s = 0.f;
        #pragma unroll
        for (int jt = 0; jt < 4; ++jt) {
            const float* wp = W_out + o * HH + 32 * (jt >> 1) + 8 * g + 4 * (jt & 1);
            float4 wv = *(const float4*)wp;
            s += th[jt][0] * wv.x + th[jt][1] * wv.y +
                 th[jt][2] * wv.z + th[jt][3] * wv.w;
        }
        s += __shfl_xor(s, 16);
        s += __shfl_xor(s, 32);
        po[o] = s;
    }
    if (g == 0) {
        #pragma unroll
        for (int o = 0; o < OO; ++o)
            out[(size_t)bglob * OO + o] = po[o] + b_out[o];
    }
}

extern "C" void kernel_launch(void* const* d_in, const int* in_sizes, int n_in,
                              void* d_out, int out_size, void* d_ws, size_t ws_size,
                              hipStream_t stream) {
    const float* X     = (const float*)d_in[0];
    const float* W_ih  = (const float*)d_in[1];
    const float* W_hh  = (const float*)d_in[2];
    const float* b_ih  = (const float*)d_in[3];
    const float* b_hh  = (const float*)d_in[4];
    const float* W_out = (const float*)d_in[5];
    const float* b_out = (const float*)d_in[6];
    float* out = (float*)d_out;

    const int B = in_sizes[0] / (TT * II);   // 32768
    dim3 grid(B / 64), block(256);           // 4 waves x 16 batch elems per block
    hipLaunchKernelGGL(rnn_mfma12, grid, block, 0, stream,
                       X, W_ih, W_hh, b_ih, b_hh, W_out, b_out, out);
}

// Round 16
// 63.995 us; speedup vs baseline: 1.1823x; 1.0657x over previous
//
#include <hip/hip_runtime.h>

#define TT 28
#define II 28
#define HH 64
#define OO 10

typedef __attribute__((ext_vector_type(8))) __bf16 bf16x8;
typedef __attribute__((ext_vector_type(2))) __bf16 bf16x2;
typedef __attribute__((ext_vector_type(4))) float f32x4;
typedef __attribute__((ext_vector_type(4))) unsigned int u32x4;

#define MFMA(A, B, C) __builtin_amdgcn_mfma_f32_16x16x32_bf16((A), (B), (C), 0, 0, 0)

__device__ __forceinline__ unsigned cvtpk(float lo, float hi) {
    bf16x2 p; p.x = (__bf16)lo; p.y = (__bf16)hi;   // v_cvt_pk_bf16_f32 (RTNE)
    return __builtin_bit_cast(unsigned, p);
}

struct PK3 { unsigned p0, p1, p2; };
// 3-limb bf16 pair split: residuals exact, total representation error O(2^-27).
__device__ __forceinline__ PK3 split3pk(float a, float b) {
    PK3 r;
    r.p0 = cvtpk(a, b);
    float a0 = __builtin_bit_cast(float, r.p0 << 16);
    float b0 = __builtin_bit_cast(float, r.p0 & 0xFFFF0000u);
    float ra = a - a0, rb = b - b0;
    r.p1 = cvtpk(ra, rb);
    float a1 = __builtin_bit_cast(float, r.p1 << 16);
    float b1 = __builtin_bit_cast(float, r.p1 & 0xFFFF0000u);
    r.p2 = cvtpk(ra - a1, rb - b1);
    return r;
}
__device__ __forceinline__ bf16x8 asbf(u32x4 u) {
    return __builtin_bit_cast(bf16x8, u);
}

// Transposed-recurrence MFMA RNN, permuted rows, 3-limb numerics (r13/r15
// arithmetic, bit-identical limbs). Round 16: W fragment tables staged in LDS
// ONCE per block (they depend only on lane, not wave -> shared by all 4 waves),
// t-loop streams them via conflict-free lane-contiguous ds_read_b128. This
// removes the per-step W rematerialization (~530 VALU instrs + ~48 cache loads
// per wave per step) that r13/r15 proved the register allocator insists on.
// SINGLE-WAVE recurrence (j/k-split: 0 for 5). One barrier total.
// tanh: proven ocml __expf path (raw v_exp_f32 insufficient - r10).
__global__ __attribute__((amdgpu_waves_per_eu(2, 2))) __launch_bounds__(256)
void rnn_mfma13(
    const float* __restrict__ X, const float* __restrict__ W_ih,
    const float* __restrict__ W_hh, const float* __restrict__ b_ih,
    const float* __restrict__ b_hh, const float* __restrict__ W_out,
    const float* __restrict__ b_out, float* __restrict__ out)
{
    const int lane = threadIdx.x & 63;
    const int wave = threadIdx.x >> 6;
    const int m15  = lane & 15;        // batch col for B/C, row-within-tile for A
    const int g    = lane >> 4;        // k-group / C row-group
    const int bglob = blockIdx.x * 64 + wave * 16 + m15;
    const int rowhi = 8 * (m15 >> 2) + (m15 & 3);   // permuted-row component

    __shared__ bf16x8 sWhh[4][2][3][64];   // [jt][kb][limb][lane], 24 KB
    __shared__ bf16x8 sWih[4][3][64];      // [jt][limb][lane],     12 KB

    // ---- stage W fragment tables: 12 groups split across 4 waves ----
    for (int grp = wave; grp < 12; grp += 4) {
        if (grp < 8) {
            const int jt = grp >> 1, kb = grp & 1;
            const int jA = 32 * (jt >> 1) + 4 * (jt & 1) + rowhi;
            const float* p = W_hh + jA * HH + 32 * kb + 8 * g;
            float4 a = *(const float4*)p;
            float4 c = *(const float4*)(p + 4);
            u32x4 u0, u1, u2;
            PK3 s;
            s = split3pk(a.x, a.y); u0.x = s.p0; u1.x = s.p1; u2.x = s.p2;
            s = split3pk(a.z, a.w); u0.y = s.p0; u1.y = s.p1; u2.y = s.p2;
            s = split3pk(c.x, c.y); u0.z = s.p0; u1.z = s.p1; u2.z = s.p2;
            s = split3pk(c.z, c.w); u0.w = s.p0; u1.w = s.p1; u2.w = s.p2;
            sWhh[jt][kb][0][lane] = asbf(u0);
            sWhh[jt][kb][1][lane] = asbf(u1);
            sWhh[jt][kb][2][lane] = asbf(u2);
        } else {
            const int jt = grp - 8;
            const int jA = 32 * (jt >> 1) + 4 * (jt & 1) + rowhi;
            float wv[8];
            #pragma unroll
            for (int e = 0; e < 8; ++e) {
                int k = 8 * g + e;
                float v = 0.f;
                if (k < II)       v = W_ih[jA * II + k];
                else if (k == II) v = b_ih[jA] + b_hh[jA];
                wv[e] = v;
            }
            u32x4 u0, u1, u2;
            PK3 s;
            s = split3pk(wv[0], wv[1]); u0.x = s.p0; u1.x = s.p1; u2.x = s.p2;
            s = split3pk(wv[2], wv[3]); u0.y = s.p0; u1.y = s.p1; u2.y = s.p2;
            s = split3pk(wv[4], wv[5]); u0.z = s.p0; u1.z = s.p1; u2.z = s.p2;
            s = split3pk(wv[6], wv[7]); u0.w = s.p0; u1.w = s.p1; u2.w = s.p2;
            sWih[jt][0][lane] = asbf(u0);
            sWih[jt][1][lane] = asbf(u1);
            sWih[jt][2][lane] = asbf(u2);
        }
    }
    __syncthreads();

    const float* xbase = X + (size_t)bglob * (TT * II);

    // prefetch x for t=0 (k=28 is the bias column: x28 = 1)
    float4 xr0, xr1;
    {
        const float* p = xbase + 8 * g;
        xr0 = *(const float4*)p;
        xr1 = (g < 3) ? *(const float4*)(p + 4) : make_float4(1.f, 0.f, 0.f, 0.f);
    }

    bf16x8 h0[2], h1[2], h2[2];   // h B-fragments (3-limb), valid for t>=1
    float th[4][4];

    for (int t = 0; t < TT; ++t) {
        // ---- x B-fragments (3-limb, pair-packed) ----
        bf16x8 xs0, xs1, xs2;
        {
            u32x4 u0, u1, u2;
            PK3 s;
            s = split3pk(xr0.x, xr0.y); u0.x = s.p0; u1.x = s.p1; u2.x = s.p2;
            s = split3pk(xr0.z, xr0.w); u0.y = s.p0; u1.y = s.p1; u2.y = s.p2;
            s = split3pk(xr1.x, xr1.y); u0.z = s.p0; u1.z = s.p1; u2.z = s.p2;
            s = split3pk(xr1.z, xr1.w); u0.w = s.p0; u1.w = s.p1; u2.w = s.p2;
            xs0 = asbf(u0); xs1 = asbf(u1); xs2 = asbf(u2);
        }

        // prefetch next t
        if (t < TT - 1) {
            const float* p = xbase + (t + 1) * II + 8 * g;
            xr0 = *(const float4*)p;
            xr1 = (g < 3) ? *(const float4*)(p + 4) : make_float4(1.f, 0.f, 0.f, 0.f);
        }

        // ---- per tile: stream W frags from LDS; same MFMA order as r13 ----
        #pragma unroll
        for (int jt = 0; jt < 4; ++jt) {
            bf16x8 wi0 = sWih[jt][0][lane];
            bf16x8 wi1 = sWih[jt][1][lane];
            bf16x8 wi2 = sWih[jt][2][lane];
            f32x4 aX = {0.f, 0.f, 0.f, 0.f};
            aX = MFMA(wi0, xs0, aX);
            aX = MFMA(wi0, xs1, aX);
            aX = MFMA(wi1, xs0, aX);
            aX = MFMA(wi0, xs2, aX);
            aX = MFMA(wi1, xs1, aX);
            aX = MFMA(wi2, xs0, aX);
            if (t > 0) {
                f32x4 aH = {0.f, 0.f, 0.f, 0.f};
                #pragma unroll
                for (int kb = 0; kb < 2; ++kb) {
                    bf16x8 wa0 = sWhh[jt][kb][0][lane];
                    bf16x8 wa1 = sWhh[jt][kb][1][lane];
                    bf16x8 wa2 = sWhh[jt][kb][2][lane];
                    aH = MFMA(wa0, h0[kb], aH);
                    aH = MFMA(wa0, h1[kb], aH);
                    aH = MFMA(wa1, h0[kb], aH);
                    aH = MFMA(wa0, h2[kb], aH);
                    aH = MFMA(wa1, h1[kb], aH);
                    aH = MFMA(wa2, h0[kb], aH);
                }
                aX = aX + aH;
            }
            // ---- tanh: PROVEN ocml path ----
            #pragma unroll
            for (int r = 0; r < 4; ++r) {
                float aa = aX[r];
                float e = __expf(2.f * aa);
                th[jt][r] = 1.f - 2.f * __builtin_amdgcn_rcpf(e + 1.f);
            }
        }

        // ---- next-step h B-fragments: lane-local, 3-limb, pair-packed ----
        if (t < TT - 1) {
            #pragma unroll
            for (int kb = 0; kb < 2; ++kb) {
                u32x4 u0, u1, u2;
                PK3 s;
                s = split3pk(th[2 * kb][0], th[2 * kb][1]);
                u0.x = s.p0; u1.x = s.p1; u2.x = s.p2;
                s = split3pk(th[2 * kb][2], th[2 * kb][3]);
                u0.y = s.p0; u1.y = s.p1; u2.y = s.p2;
                s = split3pk(th[2 * kb + 1][0], th[2 * kb + 1][1]);
                u0.z = s.p0; u1.z = s.p1; u2.z = s.p2;
                s = split3pk(th[2 * kb + 1][2], th[2 * kb + 1][3]);
                u0.w = s.p0; u1.w = s.p1; u2.w = s.p2;
                h0[kb] = asbf(u0); h1[kb] = asbf(u1); h2[kb] = asbf(u2);
            }
        }
    }

    // ---- output head: out[b,o] = h . W_out[o,:] + b_out[o] (permuted j) ----
    float po[OO];
    #pragma unroll
    for (int o = 0; o < OO; ++o) {
        float s = 0.f;
        #pragma unroll
        for (int jt = 0; jt < 4; ++jt) {
            const float* wp = W_out + o * HH + 32 * (jt >> 1) + 8 * g + 4 * (jt & 1);
            float4 wv = *(const float4*)wp;
            s += th[jt][0] * wv.x + th[jt][1] * wv.y +
                 th[jt][2] * wv.z + th[jt][3] * wv.w;
        }
        s += __shfl_xor(s, 16);
        s += __shfl_xor(s, 32);
        po[o] = s;
    }
    if (g == 0) {
        #pragma unroll
        for (int o = 0; o < OO; ++o)
            out[(size_t)bglob * OO + o] = po[o] + b_out[o];
    }
}

extern "C" void kernel_launch(void* const* d_in, const int* in_sizes, int n_in,
                              void* d_out, int out_size, void* d_ws, size_t ws_size,
                              hipStream_t stream) {
    const float* X     = (const float*)d_in[0];
    const float* W_ih  = (const float*)d_in[1];
    const float* W_hh  = (const float*)d_in[2];
    const float* b_ih  = (const float*)d_in[3];
    const float* b_hh  = (const float*)d_in[4];
    const float* W_out = (const float*)d_in[5];
    const float* b_out = (const float*)d_in[6];
    float* out = (float*)d_out;

    const int B = in_sizes[0] / (TT * II);   // 32768
    dim3 grid(B / 64), block(256);           // 4 waves x 16 batch elems per block
    hipLaunchKernelGGL(rnn_mfma13, grid, block, 0, stream,
                       X, W_ih, W_hh, b_ih, b_hh, W_out, b_out, out);
}